// Round 1
// baseline (2181.109 us; speedup 1.0000x reference)
//
#include <hip/hip_runtime.h>

// GAT_Processor: N=100000 nodes, E=1600000 edges, D=64, L=3, LeakyReLU 0.2.
// Key restructurings vs reference:
//  - (eattr @ We) @ a_e == eattr @ (We @ a_e): one pass over edge_attr yields
//    per-edge scalar scores for ALL 3 layers (edge_attr is layer-invariant).
//  - self-loop mean_attr contribution = (sum of incoming edge scores)/cnt.
//  - CSR by dst built once; per-layer softmax+aggregation is wave-per-node,
//    exact local max/sum, no atomics on the output.
//  - edge_hidden output is a pure copy, done LAST (its d_out region doubles
//    as scratch so we don't depend on ws_size).

#define D 64
#define LNUM 3
#define NEGS 0.2f

__device__ __forceinline__ float wave_sum(float v) {
  #pragma unroll
  for (int m = 1; m < 64; m <<= 1) v += __shfl_xor(v, m, 64);
  return v;
}
__device__ __forceinline__ float wave_max(float v) {
  #pragma unroll
  for (int m = 1; m < 64; m <<= 1) v = fmaxf(v, __shfl_xor(v, m, 64));
  return v;
}

__global__ void k_zero_i(int* p, int n) {
  int i = blockIdx.x * blockDim.x + threadIdx.x;
  int stride = gridDim.x * blockDim.x;
  for (; i < n; i += stride) p[i] = 0;
}

// ve[l][k] = sum_j W_edge[l][k][j] * att_edge[l][j]
__global__ void k_ve(const float* __restrict__ W_edge, const float* __restrict__ att_edge,
                     float* __restrict__ ve) {
  int i = blockIdx.x * blockDim.x + threadIdx.x;
  if (i >= LNUM * D) return;
  int l = i >> 6, k = i & 63;
  const float* Wr = W_edge + (size_t)l * D * D + (size_t)k * D;
  const float* ar = att_edge + l * D;
  float acc = 0.f;
  #pragma unroll
  for (int j = 0; j < D; j++) acc += Wr[j] * ar[j];
  ve[i] = acc;
}

__global__ void k_count(const int* __restrict__ dst, int E, int* __restrict__ cnt) {
  int e = blockIdx.x * blockDim.x + threadIdx.x;
  if (e < E) atomicAdd(&cnt[dst[e]], 1);
}

// ---- scan over deg[n] = cnt[n]+1  (self loop reserved per node) ----
__global__ void k_scan1(const int* __restrict__ cnt, int N, int* __restrict__ blockSum) {
  __shared__ int sh[512];
  int i = blockIdx.x * 512 + threadIdx.x;
  sh[threadIdx.x] = (i < N) ? cnt[i] + 1 : 0;
  __syncthreads();
  for (int off = 256; off > 0; off >>= 1) {
    if (threadIdx.x < off) sh[threadIdx.x] += sh[threadIdx.x + off];
    __syncthreads();
  }
  if (threadIdx.x == 0) blockSum[blockIdx.x] = sh[0];
}

__global__ void k_scan2(const int* __restrict__ blockSum, int* __restrict__ blockOff,
                        int NB, int* __restrict__ row_start) {
  if (threadIdx.x == 0 && blockIdx.x == 0) {
    int run = 0;
    for (int b = 0; b < NB; b++) { blockOff[b] = run; run += blockSum[b]; }
    row_start[0] = 0;
  }
}

__global__ void k_scan3(const int* __restrict__ cnt, int N, const int* __restrict__ blockOff,
                        int* __restrict__ row_start) {
  __shared__ int sh[512];
  int tid = threadIdx.x;
  int i = blockIdx.x * 512 + tid;
  sh[tid] = (i < N) ? cnt[i] + 1 : 0;
  __syncthreads();
  for (int off = 1; off < 512; off <<= 1) {
    int x = 0;
    if (tid >= off) x = sh[tid - off];
    __syncthreads();
    if (tid >= off) sh[tid] += x;
    __syncthreads();
  }
  if (i < N) row_start[i + 1] = blockOff[blockIdx.x] + sh[tid];
}

// One wave per real edge: coalesced 256B read of edge_attr row, 3 dot products
// (one per layer), CSR scatter of src + scores, self-loop mean accumulation.
__global__ __launch_bounds__(256)
void k_edgepre(const float* __restrict__ edge_attr, const int* __restrict__ srcA,
               const int* __restrict__ dstA, int E, int EP, int N,
               const float* __restrict__ ve, const int* __restrict__ row_start,
               int* __restrict__ cursor, int* __restrict__ src_sorted,
               float* __restrict__ ealpha, float* __restrict__ node_sum) {
  int lane = threadIdx.x & 63;
  int gw = (blockIdx.x * blockDim.x + threadIdx.x) >> 6;
  int nw = (gridDim.x * blockDim.x) >> 6;
  float ve0 = ve[lane], ve1 = ve[64 + lane], ve2 = ve[128 + lane];
  for (int e = gw; e < E; e += nw) {
    float a = edge_attr[(size_t)e * D + lane];
    float d0 = wave_sum(a * ve0);
    float d1 = wave_sum(a * ve1);
    float d2 = wave_sum(a * ve2);
    int pos = 0;
    if (lane == 0) {
      int dn = dstA[e];
      pos = row_start[dn] + atomicAdd(&cursor[dn], 1);
      src_sorted[pos] = srcA[e];
      atomicAdd(&node_sum[dn], d0);
      atomicAdd(&node_sum[N + dn], d1);
      atomicAdd(&node_sum[2 * N + dn], d2);
    }
    pos = __shfl(pos, 0, 64);
    if (lane == 0) ealpha[pos] = d0;
    else if (lane == 1) ealpha[EP + pos] = d1;
    else if (lane == 2) ealpha[2 * EP + pos] = d2;
  }
}

// Self loop occupies the LAST slot of each node's CSR range.
__global__ void k_selfloop(int N, int EP, const int* __restrict__ row_start,
                           const int* __restrict__ cnt, const float* __restrict__ node_sum,
                           int* __restrict__ src_sorted, float* __restrict__ ealpha) {
  int n = blockIdx.x * blockDim.x + threadIdx.x;
  if (n >= N) return;
  int slot = row_start[n + 1] - 1;
  src_sorted[slot] = n;
  float inv = 1.0f / (float)max(cnt[n], 1);
  ealpha[slot] = node_sum[n] * inv;
  ealpha[EP + slot] = node_sum[N + n] * inv;
  ealpha[2 * EP + slot] = node_sum[2 * N + n] * inv;
}

// h = x @ W[l]; s = h . att_src; t = h . att_dst.  Wave-per-row, W in LDS.
__global__ __launch_bounds__(256)
void k_h(const float* __restrict__ x, const float* __restrict__ W,
         const float* __restrict__ as_, const float* __restrict__ ad_,
         int N, float* __restrict__ h, float* __restrict__ s, float* __restrict__ t) {
  __shared__ float Wl[D * D];
  int tid = threadIdx.x;
  for (int i = tid; i < D * D; i += 256) Wl[i] = W[i];
  __syncthreads();
  int lane = tid & 63;
  int wid = tid >> 6;
  float av = as_[lane], dv = ad_[lane];
  int nwaves = gridDim.x * 4;
  for (int n = blockIdx.x * 4 + wid; n < N; n += nwaves) {
    float xv = x[(size_t)n * D + lane];
    float acc = 0.f;
    #pragma unroll
    for (int k = 0; k < D; k++) acc += __shfl(xv, k, 64) * Wl[k * D + lane];
    h[(size_t)n * D + lane] = acc;
    float ssum = wave_sum(acc * av);
    float tsum = wave_sum(acc * dv);
    if (lane == 0) { s[n] = ssum; t[n] = tsum; }
  }
}

// Wave per node: exact local softmax over incoming edges, then aggregation
// (lane j owns output column j; 256B coalesced gathers of h[src]).
__global__ __launch_bounds__(256)
void k_agg(int N, const int* __restrict__ row_start, const int* __restrict__ src_sorted,
           const float* __restrict__ ealpha, const float* __restrict__ s,
           const float* __restrict__ t, const float* __restrict__ h,
           const float* __restrict__ bias, float* __restrict__ out, int do_relu) {
  int lane = threadIdx.x & 63;
  int wid = threadIdx.x >> 6;
  int n = blockIdx.x * 4 + wid;
  if (n >= N) return;
  int rs = row_start[n], re = row_start[n + 1];
  int deg = re - rs;
  float tn = t[n];
  float acc = 0.f;
  if (deg <= 64) {
    int si = 0;
    float alpha = -1e30f;
    if (lane < deg) {
      int e = rs + lane;
      si = src_sorted[e];
      float a = s[si] + tn + ealpha[e];
      alpha = (a >= 0.f) ? a : NEGS * a;
    }
    float M = wave_max(alpha);
    float ea = (lane < deg) ? __expf(alpha - M) : 0.f;
    float denom = wave_sum(ea);
    float coef = ea / denom;
    for (int i = 0; i < deg; i++) {
      float c = __shfl(coef, i, 64);
      int sidx = __shfl(si, i, 64);
      acc += c * h[(size_t)sidx * D + lane];
    }
  } else {  // rare fallback (deg > 64)
    float m = -1e30f;
    for (int i = rs + lane; i < re; i += 64) {
      float a = s[src_sorted[i]] + tn + ealpha[i];
      a = (a >= 0.f) ? a : NEGS * a;
      m = fmaxf(m, a);
    }
    float M = wave_max(m);
    float se = 0.f;
    for (int i = rs + lane; i < re; i += 64) {
      float a = s[src_sorted[i]] + tn + ealpha[i];
      a = (a >= 0.f) ? a : NEGS * a;
      se += __expf(a - M);
    }
    float denom = wave_sum(se);
    for (int i = rs; i < re; i++) {
      int sidx = src_sorted[i];
      float a = s[sidx] + tn + ealpha[i];
      a = (a >= 0.f) ? a : NEGS * a;
      float c = __expf(a - M) / denom;
      acc += c * h[(size_t)sidx * D + lane];
    }
  }
  float o = acc + bias[lane];
  if (do_relu) o = fmaxf(o, 0.f);
  out[(size_t)n * D + lane] = o;
}

__global__ void k_copy4(const float4* __restrict__ in, float4* __restrict__ out, size_t n4) {
  size_t i = (size_t)blockIdx.x * blockDim.x + threadIdx.x;
  size_t stride = (size_t)gridDim.x * blockDim.x;
  for (; i < n4; i += stride) out[i] = in[i];
}

extern "C" void kernel_launch(void* const* d_in, const int* in_sizes, int n_in,
                              void* d_out, int out_size, void* d_ws, size_t ws_size,
                              hipStream_t stream) {
  const float* node_hidden = (const float*)d_in[0];
  const float* edge_hidden = (const float*)d_in[1];
  const float* edge_attr   = (const float*)d_in[2];
  const int*   edge_index  = (const int*)d_in[3];
  const float* W           = (const float*)d_in[4];
  const float* W_edge      = (const float*)d_in[5];
  const float* att_src     = (const float*)d_in[6];
  const float* att_dst     = (const float*)d_in[7];
  const float* att_edge    = (const float*)d_in[8];
  const float* bias        = (const float*)d_in[9];

  const int N = in_sizes[0] / D;
  const int E = in_sizes[3] / 2;
  const int EP = E + N;
  const int* srcA = edge_index;
  const int* dstA = edge_index + E;
  float* out = (float*)d_out;

  // Scratch lives in the edge_hidden region of d_out (409.6 MB >> 82 MB needed);
  // the final copy kernel overwrites it last. ws_size is never relied on.
  char* p = (char*)(out + (size_t)N * D);
  auto carve = [&](size_t bytes) { char* r = p; p += (bytes + 255) & ~(size_t)255; return r; };
  int*   cnt        = (int*)  carve((size_t)N * 4);
  int*   cursor     = (int*)  carve((size_t)N * 4);
  float* node_sum   = (float*)carve((size_t)3 * N * 4);
  int*   row_start  = (int*)  carve((size_t)(N + 1) * 4);
  int*   blockSum   = (int*)  carve(4096 * 4);
  int*   blockOff   = (int*)  carve(4096 * 4);
  float* ve         = (float*)carve(LNUM * D * 4);
  int*   src_sorted = (int*)  carve((size_t)EP * 4);
  float* ealpha     = (float*)carve((size_t)3 * EP * 4);
  float* h          = (float*)carve((size_t)N * D * 4);
  float* sv         = (float*)carve((size_t)N * 4);
  float* tv         = (float*)carve((size_t)N * 4);
  float* xA         = (float*)carve((size_t)N * D * 4);

  // zero the accumulated buffers (d_out/d_ws are poisoned before every call)
  k_zero_i<<<256, 256, 0, stream>>>(cnt, N);
  k_zero_i<<<256, 256, 0, stream>>>(cursor, N);
  k_zero_i<<<256, 256, 0, stream>>>((int*)node_sum, 3 * N);

  k_ve<<<1, 256, 0, stream>>>(W_edge, att_edge, ve);
  k_count<<<(E + 255) / 256, 256, 0, stream>>>(dstA, E, cnt);

  int NB = (N + 511) / 512;
  k_scan1<<<NB, 512, 0, stream>>>(cnt, N, blockSum);
  k_scan2<<<1, 1, 0, stream>>>(blockSum, blockOff, NB, row_start);
  k_scan3<<<NB, 512, 0, stream>>>(cnt, N, blockOff, row_start);

  k_edgepre<<<8192, 256, 0, stream>>>(edge_attr, srcA, dstA, E, EP, N, ve,
                                      row_start, cursor, src_sorted, ealpha, node_sum);
  k_selfloop<<<(N + 255) / 256, 256, 0, stream>>>(N, EP, row_start, cnt, node_sum,
                                                  src_sorted, ealpha);

  const float* xin = node_hidden;
  for (int l = 0; l < LNUM; l++) {
    k_h<<<2048, 256, 0, stream>>>(xin, W + (size_t)l * D * D, att_src + l * D,
                                  att_dst + l * D, N, h, sv, tv);
    float* xout = (l == LNUM - 1) ? out : xA;
    k_agg<<<(N + 3) / 4, 256, 0, stream>>>(N, row_start, src_sorted,
                                           ealpha + (size_t)l * EP, sv, tv, h,
                                           bias + l * D, xout, (l < LNUM - 1) ? 1 : 0);
    xin = xA;
  }

  // Last: emit the pass-through edge_hidden output (overwrites all scratch).
  k_copy4<<<8192, 256, 0, stream>>>((const float4*)edge_hidden,
                                    (float4*)(out + (size_t)N * D), (size_t)E * D / 4);
}